// Round 6
// baseline (187.089 us; speedup 1.0000x reference)
//
#include <hip/hip_runtime.h>
#include <hip/hip_bf16.h>
#include <cstdint>

// ---------------------------------------------------------------------------
// MLPDecoder: logit[e] = relu([zu, zv, |zu-zv|] @ W1 + b1) @ W2 + b2
// Round-6: single edge kernel does full K=384 (r1 algebra) in the r5
// high-occupancy structure. Gather = zb[u], zb[v] only (512 B/edge, the
// irreducible minimum for the nonlinear |zu-zv| term). Wp (96 KB) stays
// L2-resident; per-block W traffic 96 KB is amortized over 32 edges.
//   K-prep (one kernel): blocks [0,24) pack W1 -> MFMA B-frag bf16;
//                        blocks [24,..) cast z -> zb bf16.
//   K-edge: ET=32, 8 thr/edge, 2 barriers:
//     stage zu|zv -> LDS (subs 0-3 u-chunks, 4-7 v-chunks, 64B each)
//     build |zu-zv| -> LDS rows 256..383
//     MFMA 2mt x 2nt x 12ks per wave; epilogue fuses +b1, relu, dot W2,
//     16-lane butterfly, cross-wave LDS reduce.
// __launch_bounds__(256,4): VGPR cap 128 (r4 lesson: (256,8) -> spill).
// LDS 25.6 KB -> 6 blocks/CU (24 waves).
// ---------------------------------------------------------------------------

typedef __bf16 bf16_t;
typedef __bf16 bf16x8 __attribute__((ext_vector_type(8)));
typedef float  floatx4 __attribute__((ext_vector_type(4)));

#define DIM 128
#define LDA3 392             // 384 + 8 pad elems -> 784B rows
#define ET 32                // edges per block
#define N_KSTEP 12
#define N_NTILE 8
#define PACKBLK 24           // 12*8*64/256

__device__ inline float bflo(unsigned w) { return __uint_as_float(w << 16); }
__device__ inline float bfhi(unsigned w) { return __uint_as_float(w & 0xffff0000u); }

// ===========================================================================
// prep: pack W1 (blocks 0..23) + cast z->bf16 (remaining blocks)
// ===========================================================================
__global__ __launch_bounds__(256)
void prep_kernel(const float* __restrict__ z, const float* __restrict__ W1,
                 bf16_t* __restrict__ zb, bf16_t* __restrict__ Wp, int nelem) {
    const int tid = threadIdx.x;
    if ((int)blockIdx.x < PACKBLK) {
        int f = (int)blockIdx.x * 256 + tid;        // 0 .. 12*8*64-1
        int lane = f & 63;
        int nt   = (f >> 6) & 7;
        int ks   = f >> 9;
        int n  = nt * 16 + (lane & 15);
        int k0 = ks * 32 + (lane >> 4) * 8;
        bf16x8 o;
#pragma unroll
        for (int j = 0; j < 8; ++j) o[j] = (bf16_t)W1[(k0 + j) * DIM + n];
        reinterpret_cast<bf16x8*>(Wp)[f] = o;
        return;
    }
    int idx = (((int)blockIdx.x - PACKBLK) * 256 + tid) * 8;
    if (idx + 8 > nelem) return;
    const float4* src = reinterpret_cast<const float4*>(z + idx);
    float4 a = src[0], b = src[1];
    bf16x8 o;
    o[0]=(bf16_t)a.x; o[1]=(bf16_t)a.y; o[2]=(bf16_t)a.z; o[3]=(bf16_t)a.w;
    o[4]=(bf16_t)b.x; o[5]=(bf16_t)b.y; o[6]=(bf16_t)b.z; o[7]=(bf16_t)b.w;
    *reinterpret_cast<bf16x8*>(zb + idx) = o;
}

// ===========================================================================
// edge kernel
// ===========================================================================
__global__ __launch_bounds__(256, 4)
void edge_kernel(const bf16_t* __restrict__ zb,
                 const bf16_t* __restrict__ Wp,
                 const int* __restrict__ ei,
                 const float* __restrict__ b1,
                 const float* __restrict__ W2,
                 const float* __restrict__ b2,
                 float* __restrict__ out, int E) {
    __shared__ __align__(16) bf16_t A[ET * LDA3];   // 25088 B
    __shared__ float red[4][ET];                    // 512 B

    const int tid = threadIdx.x;
    const int ebase = (int)blockIdx.x * ET;
    const int el  = tid >> 3;        // edge 0..31
    const int sub = tid & 7;         // 0..7
    const int which = sub >> 2;      // 0: u-side, 1: v-side
    const int chunk = sub & 3;       // 64B chunk 0..3

    int e = ebase + el; if (e >= E) e = E - 1;
    int node = ei[which * E + e];

    // ---- gather one 64B chunk of zb[node]; write to A[k = which*128 + c] ----
    const uint4* p = reinterpret_cast<const uint4*>(
        zb + (size_t)node * DIM + chunk * 32);
    uint4 g[4];
#pragma unroll
    for (int j = 0; j < 4; ++j) g[j] = p[j];

    const int wave = tid >> 6, lane = tid & 63;
    const int l15 = lane & 15, quad = lane >> 4;

    float b1v[2], w2v[2];
#pragma unroll
    for (int nt = 0; nt < 2; ++nt) {
        int n = (wave * 2 + nt) * 16 + l15;
        b1v[nt] = b1[n];
        w2v[nt] = W2[n];
    }

    bf16_t* dst = &A[el * LDA3 + which * DIM + chunk * 32];
#pragma unroll
    for (int j = 0; j < 4; ++j)
        *reinterpret_cast<uint4*>(dst + j * 8) = g[j];
    __syncthreads();

    // ---- |zu - zv| -> rows 256..383  (32 edges x 16 chunk8 = 512; 2/thread)
#pragma unroll
    for (int i = 0; i < 2; ++i) {
        int idx = i * 256 + tid;
        int m  = idx >> 4;
        int cc = (idx & 15) * 8;
        uint4 au = *reinterpret_cast<const uint4*>(&A[m * LDA3 + cc]);
        uint4 av = *reinterpret_cast<const uint4*>(&A[m * LDA3 + DIM + cc]);
        bf16x8 d;
        d[0]=(bf16_t)fabsf(bflo(au.x)-bflo(av.x));
        d[1]=(bf16_t)fabsf(bfhi(au.x)-bfhi(av.x));
        d[2]=(bf16_t)fabsf(bflo(au.y)-bflo(av.y));
        d[3]=(bf16_t)fabsf(bfhi(au.y)-bfhi(av.y));
        d[4]=(bf16_t)fabsf(bflo(au.z)-bflo(av.z));
        d[5]=(bf16_t)fabsf(bfhi(au.z)-bfhi(av.z));
        d[6]=(bf16_t)fabsf(bflo(au.w)-bflo(av.w));
        d[7]=(bf16_t)fabsf(bfhi(au.w)-bfhi(av.w));
        *reinterpret_cast<bf16x8*>(&A[m * LDA3 + 2 * DIM + cc]) = d;
    }
    __syncthreads();

    // ---- MFMA: 2 m-tiles x 2 n-tiles per wave, K=384 ----
    floatx4 acc[2][2];
#pragma unroll
    for (int mt = 0; mt < 2; ++mt)
#pragma unroll
        for (int nt = 0; nt < 2; ++nt) acc[mt][nt] = (floatx4)0.0f;

    const bf16x8* WpF = reinterpret_cast<const bf16x8*>(Wp);
#pragma unroll
    for (int ks = 0; ks < N_KSTEP; ++ks) {
        bf16x8 bfrag[2];
#pragma unroll
        for (int nt = 0; nt < 2; ++nt)
            bfrag[nt] = WpF[(ks * N_NTILE + wave * 2 + nt) * 64 + lane];
#pragma unroll
        for (int mt = 0; mt < 2; ++mt) {
            bf16x8 afrag = *reinterpret_cast<const bf16x8*>(
                &A[(mt * 16 + l15) * LDA3 + ks * 32 + quad * 8]);
#pragma unroll
            for (int nt = 0; nt < 2; ++nt)
                acc[mt][nt] = __builtin_amdgcn_mfma_f32_16x16x32_bf16(
                    afrag, bfrag[nt], acc[mt][nt], 0, 0, 0);
        }
    }

    // ---- epilogue: +b1, relu, dot W2, 16-lane butterfly, cross-wave sum ----
#pragma unroll
    for (int mt = 0; mt < 2; ++mt)
#pragma unroll
        for (int r = 0; r < 4; ++r) {
            int m = mt * 16 + quad * 4 + r;
            float s = 0.f;
#pragma unroll
            for (int nt = 0; nt < 2; ++nt) {
                float h = acc[mt][nt][r] + b1v[nt];
                h = fmaxf(h, 0.f);
                s += h * w2v[nt];
            }
            s += __shfl_xor(s, 1);
            s += __shfl_xor(s, 2);
            s += __shfl_xor(s, 4);
            s += __shfl_xor(s, 8);
            if (l15 == 0) red[wave][m] = s;
        }
    __syncthreads();

    if (tid < ET) {
        int eo = ebase + tid;
        if (eo < E) out[eo] = red[0][tid] + red[1][tid] + red[2][tid] + red[3][tid] + b2[0];
    }
}

// ===========================================================================
// Fallback (gathers fp32 z directly; needs only 96 KB ws) — r1-proven.
// ===========================================================================
#define E_TILE 64
#define ROW_ELEMS 392

__global__ __launch_bounds__(256)
void decode_fallback(const float* __restrict__ zsrc,
                     const int* __restrict__ ei,
                     const bf16_t* __restrict__ Wp,
                     const float* __restrict__ b1,
                     const float* __restrict__ W2,
                     const float* __restrict__ b2,
                     float* __restrict__ out, int E) {
    __shared__ __align__(16) bf16_t Atile[E_TILE * ROW_ELEMS];
    __shared__ float red[2][E_TILE];
    const int tid = threadIdx.x;
    const int ebase = blockIdx.x * E_TILE;
#pragma unroll
    for (int i = 0; i < 8; ++i) {
        int half  = i * 16 + (tid >> 4);
        int m     = half >> 1;
        int which = half & 1;
        int e = ebase + m; if (e >= E) e = E - 1;
        int node = ei[which * E + e];
        int l16 = tid & 15;
        bf16_t* dst = &Atile[m * ROW_ELEMS + which * DIM + l16 * 8];
        const float4* src = reinterpret_cast<const float4*>(
            zsrc + (size_t)node * DIM + l16 * 8);
        float4 a = src[0], b = src[1];
        bf16x8 o;
        o[0]=(bf16_t)a.x; o[1]=(bf16_t)a.y; o[2]=(bf16_t)a.z; o[3]=(bf16_t)a.w;
        o[4]=(bf16_t)b.x; o[5]=(bf16_t)b.y; o[6]=(bf16_t)b.z; o[7]=(bf16_t)b.w;
        *reinterpret_cast<bf16x8*>(dst) = o;
    }
    __syncthreads();
#pragma unroll
    for (int i = 0; i < 4; ++i) {
        int chunk = i * 256 + tid;
        int m  = chunk >> 4;
        int cc = (chunk & 15) * 8;
        uint4 au = *reinterpret_cast<const uint4*>(&Atile[m * ROW_ELEMS + cc]);
        uint4 av = *reinterpret_cast<const uint4*>(&Atile[m * ROW_ELEMS + DIM + cc]);
        bf16x8 d;
        d[0]=(bf16_t)fabsf(bflo(au.x)-bflo(av.x));
        d[1]=(bf16_t)fabsf(bfhi(au.x)-bfhi(av.x));
        d[2]=(bf16_t)fabsf(bflo(au.y)-bflo(av.y));
        d[3]=(bf16_t)fabsf(bfhi(au.y)-bfhi(av.y));
        d[4]=(bf16_t)fabsf(bflo(au.z)-bflo(av.z));
        d[5]=(bf16_t)fabsf(bfhi(au.z)-bfhi(av.z));
        d[6]=(bf16_t)fabsf(bflo(au.w)-bflo(av.w));
        d[7]=(bf16_t)fabsf(bfhi(au.w)-bfhi(av.w));
        *reinterpret_cast<bf16x8*>(&Atile[m * ROW_ELEMS + 2 * DIM + cc]) = d;
    }
    __syncthreads();
    const int wave = tid >> 6, lane = tid & 63;
    const int wm = wave >> 1, wn = wave & 1;
    const int l15 = lane & 15, quad = lane >> 4;
    floatx4 acc[2][4];
#pragma unroll
    for (int mt = 0; mt < 2; ++mt)
#pragma unroll
        for (int nt = 0; nt < 4; ++nt) acc[mt][nt] = (floatx4)0.0f;
    float b1v[4], w2v[4];
#pragma unroll
    for (int nt = 0; nt < 4; ++nt) {
        int n = (wn * 4 + nt) * 16 + l15;
        b1v[nt] = b1[n];
        w2v[nt] = W2[n];
    }
    const bf16x8* WpF = reinterpret_cast<const bf16x8*>(Wp);
#pragma unroll
    for (int ks = 0; ks < N_KSTEP; ++ks) {
        bf16x8 bfrag[4];
#pragma unroll
        for (int nt = 0; nt < 4; ++nt)
            bfrag[nt] = WpF[(ks * N_NTILE + wn * 4 + nt) * 64 + lane];
#pragma unroll
        for (int mt = 0; mt < 2; ++mt) {
            int m = wm * 32 + mt * 16 + l15;
            bf16x8 afrag = *reinterpret_cast<const bf16x8*>(
                &Atile[m * ROW_ELEMS + ks * 32 + quad * 8]);
#pragma unroll
            for (int nt = 0; nt < 4; ++nt)
                acc[mt][nt] = __builtin_amdgcn_mfma_f32_16x16x32_bf16(
                    afrag, bfrag[nt], acc[mt][nt], 0, 0, 0);
        }
    }
    float partial[2][4];
#pragma unroll
    for (int mt = 0; mt < 2; ++mt)
#pragma unroll
        for (int r = 0; r < 4; ++r) {
            float s = 0.f;
#pragma unroll
            for (int nt = 0; nt < 4; ++nt) {
                float h = acc[mt][nt][r] + b1v[nt];
                h = fmaxf(h, 0.f);
                s += h * w2v[nt];
            }
            s += __shfl_xor(s, 1);
            s += __shfl_xor(s, 2);
            s += __shfl_xor(s, 4);
            s += __shfl_xor(s, 8);
            partial[mt][r] = s;
        }
    if (l15 == 0) {
#pragma unroll
        for (int mt = 0; mt < 2; ++mt)
#pragma unroll
            for (int r = 0; r < 4; ++r) {
                int m = wm * 32 + mt * 16 + quad * 4 + r;
                red[wn][m] = partial[mt][r];
            }
    }
    __syncthreads();
    if (tid < E_TILE) {
        int e = ebase + tid;
        if (e < E) out[e] = red[0][tid] + red[1][tid] + b2[0];
    }
}

// ===========================================================================
extern "C" void kernel_launch(void* const* d_in, const int* in_sizes, int n_in,
                              void* d_out, int out_size, void* d_ws, size_t ws_size,
                              hipStream_t stream) {
    const float* z  = (const float*)d_in[0];
    const int*   ei = (const int*)d_in[1];
    const float* W1 = (const float*)d_in[2];
    const float* b1 = (const float*)d_in[3];
    const float* W2 = (const float*)d_in[4];
    const float* b2 = (const float*)d_in[5];
    float* out = (float*)d_out;

    const int E     = in_sizes[1] / 2;
    const int nelem = in_sizes[0];                 // Nn * DIM

    const size_t wp_bytes = (size_t)N_KSTEP * N_NTILE * 64 * 16;   // 96 KB
    const size_t zb_bytes = (size_t)nelem * sizeof(bf16_t);        // 25.6 MB

    bf16_t* wp = (bf16_t*)d_ws;

    if (ws_size >= wp_bytes + zb_bytes) {
        bf16_t* zbuf = (bf16_t*)((char*)d_ws + wp_bytes);
        const int castblk = (nelem / 8 + 255) / 256;
        hipLaunchKernelGGL(prep_kernel, dim3(PACKBLK + castblk), dim3(256),
                           0, stream, z, W1, zbuf, wp, nelem);
        const int eblocks = (E + ET - 1) / ET;
        hipLaunchKernelGGL(edge_kernel, dim3(eblocks), dim3(256), 0, stream,
                           zbuf, wp, ei, b1, W2, b2, out, E);
    } else {
        hipLaunchKernelGGL(prep_kernel, dim3(PACKBLK), dim3(256),
                           0, stream, z, W1, (bf16_t*)nullptr, wp, 0);
        const int eblocks = (E + E_TILE - 1) / E_TILE;
        hipLaunchKernelGGL(decode_fallback, dim3(eblocks), dim3(256), 0, stream,
                           z, ei, wp, b1, W2, b2, out, E);
    }
}